// Round 4
// baseline (277.654 us; speedup 1.0000x reference)
//
#include <hip/hip_runtime.h>

typedef __attribute__((ext_vector_type(8))) short short8;
typedef __attribute__((ext_vector_type(4))) float floatx4;

static __device__ __forceinline__ unsigned short f2bf(float f) {
    unsigned u = __float_as_uint(f);
    u += 0x7FFFu + ((u >> 16) & 1u);
    return (unsigned short)(u >> 16);
}

// ---------------- kernel 0: convert weights fp32 -> bf16 into ws ----------------
__global__ __launch_bounds__(256) void convert_w_k(const float* __restrict__ W1,
                                                   const float* __restrict__ W2,
                                                   unsigned short* __restrict__ w1b,
                                                   unsigned short* __restrict__ w2b) {
    int i = blockIdx.x * 256 + threadIdx.x;  // 16384 threads, exact
    w1b[i] = f2bf(W1[i]);
    w2b[i] = f2bf(W2[i]);
}

// ---------------- fused kernel: Newton solve + MLP, zero in-loop barriers ----------------
// 256 threads = 4 waves; each tile = 64 samples, wave w owns rows w*16..w*16+15.
// Newton: 4 threads/sample (quad shuffles). All newton->mlp dataflow is
// wave-private: xs goes through a wave-private LDS strip (in-order same-wave
// LDS), e^s moves by intra-wave __shfl. Weights: W1 staged once per block in
// LDS (swizzled); W2 B-frags read straight from global (32KB, L1-resident).
// LDS = 32KB (sW1) + 8KB (sXH, Xs/H aliased) = 40KB -> 4 blocks/CU -> 4
// waves/SIMD for the exp-chain latency. Newton is VALU/trans-pipe, MLP is
// MFMA/LDS-pipe: fully co-scheduled across desynced waves (m114).
__global__ __launch_bounds__(256, 4) void fused_k(const float* __restrict__ x,
                                                  const float* __restrict__ r,
                                                  const unsigned short* __restrict__ w1b,
                                                  const unsigned short* __restrict__ w2b,
                                                  const float* __restrict__ b1,
                                                  const float* __restrict__ b2,
                                                  float* __restrict__ out,
                                                  int tiles_per_block) {
    __shared__ unsigned short sW1[256 * 64];  // 32 KB, [h][k] bf16, swizzled
    __shared__ unsigned short sXH[64 * 64];   //  8 KB, Xs strip aliased with H strip

    int tid = threadIdx.x;

    // stage W1 [256x64] bf16 (2048 uint4), XOR-swizzled: chunk ch of row R at ch^(R&7)
    const uint4* w1u = (const uint4*)w1b;
#pragma unroll
    for (int c = 0; c < 8; ++c) {
        int g = tid + c * 256;
        int row = g >> 3, ch = g & 7;
        *(uint4*)&sW1[row * 64 + (ch ^ (row & 7)) * 8] = w1u[g];
    }
    __syncthreads();  // the only barrier in the kernel

    int wave = tid >> 6, lane = tid & 63;
    int q = lane >> 4, l16 = lane & 15;
    int sx = l16 & 7;          // swizzle key for rows indexed by l16
    int part = tid & 3;        // newton: quad part (16 coords each)
    int rloc = tid >> 2;       // newton: block-local sample row (0..63) = wave*16 + (lane>>2)

    // r is tile-invariant: load once
    const float4* r4 = (const float4*)(r + part * 16);
    float rr[16];
#pragma unroll
    for (int j = 0; j < 4; ++j) {
        float4 b = r4[j];
        rr[4 * j + 0] = b.x; rr[4 * j + 1] = b.y; rr[4 * j + 2] = b.z; rr[4 * j + 3] = b.w;
    }

    float bias1[16];
#pragma unroll
    for (int n = 0; n < 16; ++n) bias1[n] = b1[n * 16 + l16];
    float bias2[4];
#pragma unroll
    for (int n = 0; n < 4; ++n) bias2[n] = b2[n * 16 + l16];

    int myrow = wave * 16 + l16;  // mlp: A/H row
    int kx = rloc & 7;            // swizzle key for the newton-write row

    for (int tt = 0; tt < tiles_per_block; ++tt) {
        size_t m0 = ((size_t)blockIdx.x * tiles_per_block + tt) * 64;

        // ================= Newton phase (4 threads/sample) =================
        const float4* x4 = (const float4*)(x + (m0 + rloc) * 64 + part * 16);
        float xv[16], x2[16], rx2[16];
        float sum0 = 0.f, sumr = 0.f;
        int nz = 0;
#pragma unroll
        for (int j = 0; j < 4; ++j) {
            float4 a = x4[j];
            xv[4 * j + 0] = a.x; xv[4 * j + 1] = a.y; xv[4 * j + 2] = a.z; xv[4 * j + 3] = a.w;
        }
#pragma unroll
        for (int j = 0; j < 16; ++j) {
            x2[j] = xv[j] * xv[j];
            rx2[j] = rr[j] * x2[j];
            sum0 += x2[j];
            sumr += rx2[j];
            nz |= (fabsf(xv[j]) > 1e-12f) ? 1 : 0;
        }
        sum0 += __shfl_xor(sum0, 1); sum0 += __shfl_xor(sum0, 2);
        sumr += __shfl_xor(sumr, 1); sumr += __shfl_xor(sumr, 2);
        nz   |= __shfl_xor(nz, 1);   nz   |= __shfl_xor(nz, 2);

        float s = 0.f;
        if (nz) {
            // analytic init: left-of-root (weighted Jensen), Newton monotone
            s = __logf(sum0) * sum0 / (2.f * sumr);
#pragma unroll 1
            for (int it = 0; it < 11; ++it) {
                float m2s = -2.f * s;
                float v = 0.f, dv = 0.f;
#pragma unroll
                for (int j = 0; j < 16; ++j) {
                    float e = __expf(m2s * rr[j]);
                    v = fmaf(e, x2[j], v);
                    dv = fmaf(e, rx2[j], dv);
                }
                v += __shfl_xor(v, 1);   v += __shfl_xor(v, 2);
                dv += __shfl_xor(dv, 1); dv += __shfl_xor(dv, 2);
                float val = v - 1.f;  // -1 applied ONCE, post-reduction
                s += val / (2.f * dv);
            }
        }
        float es = __expf(s);  // e^{NU*s}, NU=1; valid on all 64 lanes

        // xs = x * exp(-r*s) -> bf16 -> wave-private LDS strip (swizzled)
        unsigned up[8];
#pragma unroll
        for (int j = 0; j < 8; ++j) {
            float a = xv[2 * j] * __expf(-s * rr[2 * j]);
            float b = xv[2 * j + 1] * __expf(-s * rr[2 * j + 1]);
            up[j] = (unsigned)f2bf(a) | ((unsigned)f2bf(b) << 16);
        }
        *(uint4*)&sXH[rloc * 64 + ((2 * part) ^ kx) * 8] = make_uint4(up[0], up[1], up[2], up[3]);
        *(uint4*)&sXH[rloc * 64 + ((2 * part + 1) ^ kx) * 8] = make_uint4(up[4], up[5], up[6], up[7]);

        // ================= MLP phase =================
        // A-frags (16x16x32: A[m=l16][k=q*8+j]) from the strip (same-wave, in-order)
        short8 a0 = *(const short8*)&sXH[myrow * 64 + (q ^ sx) * 8];
        short8 a1 = *(const short8*)&sXH[myrow * 64 + ((q + 4) ^ sx) * 8];
        // e^s for my 4 output rows, via intra-wave shuffle (row rw owned by lane 4*rw)
        float sc[4];
#pragma unroll
        for (int reg = 0; reg < 4; ++reg) sc[reg] = __shfl(es, (q * 4 + reg) * 4);

        floatx4 oacc[4];
#pragma unroll
        for (int n = 0; n < 4; ++n) oacc[n] = (floatx4){0.f, 0.f, 0.f, 0.f};

#pragma unroll
        for (int hc = 0; hc < 4; ++hc) {
            // ---- GEMM1: H[:, hc*64..+63] = relu(Xs @ W1^T + b1), 4 n-subtiles
#pragma unroll
            for (int n = 0; n < 4; ++n) {
                int hcol = hc * 4 + n;            // 16-col subtile (0..15)
                int row = hcol * 16 + l16;        // W1 row = h index
                short8 wb0 = *(const short8*)&sW1[row * 64 + (q ^ sx) * 8];
                short8 wb1 = *(const short8*)&sW1[row * 64 + ((q + 4) ^ sx) * 8];
                floatx4 acc = {0.f, 0.f, 0.f, 0.f};
                acc = __builtin_amdgcn_mfma_f32_16x16x32_bf16(a0, wb0, acc, 0, 0, 0);
                acc = __builtin_amdgcn_mfma_f32_16x16x32_bf16(a1, wb1, acc, 0, 0, 0);
                float bias = bias1[hcol];
#pragma unroll
                for (int reg = 0; reg < 4; ++reg) {
                    // C/D: col=l16, row=q*4+reg
                    float h = acc[reg] + bias;
                    h = h > 0.f ? h : 0.f;
                    int rw = wave * 16 + q * 4 + reg;
                    int E = n * 16 + l16;  // h-local col in the 64-chunk
                    sXH[rw * 64 + (((E >> 3) ^ (rw & 7)) * 8) + (E & 7)] = f2bf(h);
                }
            }
            // ---- GEMM2 partial: oacc += H_chunk @ W2_chunk^T (W2 frags from global/L1)
            short8 ha0 = *(const short8*)&sXH[myrow * 64 + (q ^ sx) * 8];
            short8 ha1 = *(const short8*)&sXH[myrow * 64 + ((q + 4) ^ sx) * 8];
#pragma unroll
            for (int n = 0; n < 4; ++n) {
                int row = n * 16 + l16;  // W2 row = o index
                short8 wb0 = *(const short8*)(w2b + row * 256 + hc * 64 + q * 8);
                short8 wb1 = *(const short8*)(w2b + row * 256 + hc * 64 + 32 + q * 8);
                oacc[n] = __builtin_amdgcn_mfma_f32_16x16x32_bf16(ha0, wb0, oacc[n], 0, 0, 0);
                oacc[n] = __builtin_amdgcn_mfma_f32_16x16x32_bf16(ha1, wb1, oacc[n], 0, 0, 0);
            }
        }
        // ---- epilogue: out = (H @ W2^T + b2) * e^s
#pragma unroll
        for (int n = 0; n < 4; ++n) {
#pragma unroll
            for (int reg = 0; reg < 4; ++reg) {
                float o = (oacc[n][reg] + bias2[n]) * sc[reg];
                out[(m0 + wave * 16 + q * 4 + reg) * 64 + n * 16 + l16] = o;
            }
        }
    }
}

extern "C" void kernel_launch(void* const* d_in, const int* in_sizes, int n_in,
                              void* d_out, int out_size, void* d_ws, size_t ws_size,
                              hipStream_t stream) {
    const float* x  = (const float*)d_in[0];
    const float* r  = (const float*)d_in[1];
    const float* W1 = (const float*)d_in[2];
    const float* b1 = (const float*)d_in[3];
    const float* W2 = (const float*)d_in[4];
    const float* b2 = (const float*)d_in[5];
    float* out = (float*)d_out;
    int B = in_sizes[0] / 64;  // 262144

    char* ws = (char*)d_ws;
    unsigned short* w1b = (unsigned short*)ws;            // 32768 B
    unsigned short* w2b = (unsigned short*)(ws + 32768);  // 32768 B

    convert_w_k<<<64, 256, 0, stream>>>(W1, W2, w1b, w2b);

    int tiles = B / 64;        // 4096
    int blocks = 1024;         // 4 per CU (40 KB LDS)
    int tpb = tiles / blocks;  // 4
    fused_k<<<blocks, 256, 0, stream>>>(x, r, w1b, w2b, b1, b2, out, tpb);
}

// Round 5
// 261.479 us; speedup vs baseline: 1.0619x; 1.0619x over previous
//
#include <hip/hip_runtime.h>

typedef __attribute__((ext_vector_type(8))) short short8;
typedef __attribute__((ext_vector_type(4))) float floatx4;

static __device__ __forceinline__ unsigned short f2bf(float f) {
    unsigned u = __float_as_uint(f);
    u += 0x7FFFu + ((u >> 16) & 1u);
    return (unsigned short)(u >> 16);
}

// ---------------- kernel 0: convert weights fp32 -> bf16 into ws ----------------
__global__ __launch_bounds__(256) void convert_w_k(const float* __restrict__ W1,
                                                   const float* __restrict__ W2,
                                                   unsigned short* __restrict__ w1b,
                                                   unsigned short* __restrict__ w2b) {
    int i = blockIdx.x * 256 + threadIdx.x;  // 16384 threads, exact
    w1b[i] = f2bf(W1[i]);
    w2b[i] = f2bf(W2[i]);
}

// ---------------- fused kernel: Newton solve + MLP ----------------
// 256 threads = 4 waves; tile = 64 samples, wave w owns rows w*16..+15.
// Newton: 8 threads/sample (xor-1/2/4 shuffles), TWO passes of 32 samples per
// tile -> per-thread arrays are [8] (32 transient VGPRs, not 64 — R4's
// [16] arrays + launch_bounds(,4) spilled ~460MB to scratch).
// All newton->mlp dataflow wave-private: xs via wave-private LDS strip
// (same-wave in-order), e^s via intra-wave __shfl. W1 staged once per block
// (swizzled LDS); W2 frags straight from global (32KB, L1-resident).
// LDS = 32KB + 8KB = 40KB. launch_bounds(256,3): unified VGPR cap ~170 — no
// spills at ~120 demand; 3 blocks/CU = 12 waves/CU.
__global__ __launch_bounds__(256, 3) void fused_k(const float* __restrict__ x,
                                                  const float* __restrict__ r,
                                                  const unsigned short* __restrict__ w1b,
                                                  const unsigned short* __restrict__ w2b,
                                                  const float* __restrict__ b1,
                                                  const float* __restrict__ b2,
                                                  float* __restrict__ out,
                                                  int tiles_per_block) {
    __shared__ unsigned short sW1[256 * 64];  // 32 KB, [h][k] bf16, swizzled
    __shared__ unsigned short sXH[64 * 64];   //  8 KB, Xs strip aliased with H strip

    int tid = threadIdx.x;

    // stage W1 [256x64] bf16 (2048 uint4), XOR-swizzled: chunk ch of row R at ch^(R&7)
    const uint4* w1u = (const uint4*)w1b;
#pragma unroll
    for (int c = 0; c < 8; ++c) {
        int g = tid + c * 256;
        int row = g >> 3, ch = g & 7;
        *(uint4*)&sW1[row * 64 + (ch ^ (row & 7)) * 8] = w1u[g];
    }
    __syncthreads();  // the only barrier in the kernel

    int wave = tid >> 6, lane = tid & 63;
    int q = lane >> 4, l16 = lane & 15;
    int sx = l16 & 7;        // swizzle key for rows indexed by l16
    int part = lane & 7;     // newton: coord slice (8 coords)
    int grp = lane >> 3;     // newton: sample-within-pass (0..7)

    // r slice is tile-invariant: load once
    const float4* r4 = (const float4*)(r + part * 8);
    float rr[8];
    {
        float4 b0 = r4[0], b1v = r4[1];
        rr[0] = b0.x; rr[1] = b0.y; rr[2] = b0.z; rr[3] = b0.w;
        rr[4] = b1v.x; rr[5] = b1v.y; rr[6] = b1v.z; rr[7] = b1v.w;
    }

    float bias1[16];
#pragma unroll
    for (int n = 0; n < 16; ++n) bias1[n] = b1[n * 16 + l16];
    float bias2[4];
#pragma unroll
    for (int n = 0; n < 4; ++n) bias2[n] = b2[n * 16 + l16];

    int myrow = wave * 16 + l16;  // mlp: A/H row

    for (int tt = 0; tt < tiles_per_block; ++tt) {
        size_t m0 = ((size_t)blockIdx.x * tiles_per_block + tt) * 64;

        // ================= Newton: 2 passes x 32 samples =================
        float sc[4];
#pragma unroll 1
        for (int p = 0; p < 2; ++p) {
            int rloc = wave * 16 + p * 8 + grp;  // block-local sample row
            const float4* x4 = (const float4*)(x + (m0 + rloc) * 64 + part * 8);
            float xv[8], x2[8], rx2[8];
            float4 a0v = x4[0], a1v = x4[1];
            xv[0] = a0v.x; xv[1] = a0v.y; xv[2] = a0v.z; xv[3] = a0v.w;
            xv[4] = a1v.x; xv[5] = a1v.y; xv[6] = a1v.z; xv[7] = a1v.w;

            float sum0 = 0.f, sumr = 0.f;
            int nz = 0;
#pragma unroll
            for (int j = 0; j < 8; ++j) {
                x2[j] = xv[j] * xv[j];
                rx2[j] = rr[j] * x2[j];
                sum0 += x2[j];
                sumr += rx2[j];
                nz |= (fabsf(xv[j]) > 1e-12f) ? 1 : 0;
            }
            sum0 += __shfl_xor(sum0, 1); sum0 += __shfl_xor(sum0, 2); sum0 += __shfl_xor(sum0, 4);
            sumr += __shfl_xor(sumr, 1); sumr += __shfl_xor(sumr, 2); sumr += __shfl_xor(sumr, 4);
            nz   |= __shfl_xor(nz, 1);   nz   |= __shfl_xor(nz, 2);   nz   |= __shfl_xor(nz, 4);

            float s = 0.f;
            if (nz) {
                // analytic init: left-of-root (weighted Jensen) => monotone Newton
                s = __logf(sum0) * sum0 / (2.f * sumr);
#pragma unroll 1
                for (int it = 0; it < 8; ++it) {
                    float m2s = -2.f * s;
                    float v = 0.f, dv = 0.f;
#pragma unroll
                    for (int j = 0; j < 8; ++j) {
                        float e = __expf(m2s * rr[j]);
                        v = fmaf(e, x2[j], v);
                        dv = fmaf(e, rx2[j], dv);
                    }
                    v += __shfl_xor(v, 1);   v += __shfl_xor(v, 2);   v += __shfl_xor(v, 4);
                    dv += __shfl_xor(dv, 1); dv += __shfl_xor(dv, 2); dv += __shfl_xor(dv, 4);
                    float val = v - 1.f;  // -1 ONCE, post-reduction
                    s += val / (2.f * dv);
                }
            }
            float es = __expf(s);  // e^{NU*s}, NU=1

            // xs = x * exp(-r*s) -> bf16 -> wave-private strip (swizzled)
            unsigned up[4];
#pragma unroll
            for (int j = 0; j < 4; ++j) {
                float a = xv[2 * j] * __expf(-s * rr[2 * j]);
                float b = xv[2 * j + 1] * __expf(-s * rr[2 * j + 1]);
                up[j] = (unsigned)f2bf(a) | ((unsigned)f2bf(b) << 16);
            }
            *(uint4*)&sXH[rloc * 64 + ((part ^ (rloc & 7))) * 8] =
                make_uint4(up[0], up[1], up[2], up[3]);

            // e^s for epilogue rows q*4+reg (rows 8p..8p+7 live in this pass,
            // owned by lane ((row&7)*8)); predicated keep.
#pragma unroll
            for (int reg = 0; reg < 4; ++reg) {
                float cand = __shfl(es, ((q * 4 + reg) & 7) * 8);
                if ((q >> 1) == p) sc[reg] = cand;
            }
        }

        // ================= MLP phase =================
        // A-frags (16x16x32: A[m=l16][k=q*8+j]) from strip (same-wave, in-order)
        short8 a0 = *(const short8*)&sXH[myrow * 64 + (q ^ sx) * 8];
        short8 a1 = *(const short8*)&sXH[myrow * 64 + ((q + 4) ^ sx) * 8];

        floatx4 oacc[4];
#pragma unroll
        for (int n = 0; n < 4; ++n) oacc[n] = (floatx4){0.f, 0.f, 0.f, 0.f};

#pragma unroll
        for (int hc = 0; hc < 4; ++hc) {
            // ---- GEMM1: H[:, hc*64..+63] = relu(Xs @ W1^T + b1), 4 n-subtiles
#pragma unroll
            for (int n = 0; n < 4; ++n) {
                int hcol = hc * 4 + n;            // 16-col subtile (0..15)
                int row = hcol * 16 + l16;        // W1 row = h index
                short8 wb0 = *(const short8*)&sW1[row * 64 + (q ^ sx) * 8];
                short8 wb1 = *(const short8*)&sW1[row * 64 + ((q + 4) ^ sx) * 8];
                floatx4 acc = {0.f, 0.f, 0.f, 0.f};
                acc = __builtin_amdgcn_mfma_f32_16x16x32_bf16(a0, wb0, acc, 0, 0, 0);
                acc = __builtin_amdgcn_mfma_f32_16x16x32_bf16(a1, wb1, acc, 0, 0, 0);
                float bias = bias1[hcol];
#pragma unroll
                for (int reg = 0; reg < 4; ++reg) {
                    // C/D: col=l16, row=q*4+reg
                    float h = acc[reg] + bias;
                    h = h > 0.f ? h : 0.f;
                    int rw = wave * 16 + q * 4 + reg;
                    int E = n * 16 + l16;  // h-local col in the 64-chunk
                    sXH[rw * 64 + (((E >> 3) ^ (rw & 7)) * 8) + (E & 7)] = f2bf(h);
                }
            }
            // ---- GEMM2 partial: oacc += H_chunk @ W2_chunk^T (W2 frags global/L1)
            short8 ha0 = *(const short8*)&sXH[myrow * 64 + (q ^ sx) * 8];
            short8 ha1 = *(const short8*)&sXH[myrow * 64 + ((q + 4) ^ sx) * 8];
#pragma unroll
            for (int n = 0; n < 4; ++n) {
                int row = n * 16 + l16;  // W2 row = o index
                short8 wb0 = *(const short8*)(w2b + row * 256 + hc * 64 + q * 8);
                short8 wb1 = *(const short8*)(w2b + row * 256 + hc * 64 + 32 + q * 8);
                oacc[n] = __builtin_amdgcn_mfma_f32_16x16x32_bf16(ha0, wb0, oacc[n], 0, 0, 0);
                oacc[n] = __builtin_amdgcn_mfma_f32_16x16x32_bf16(ha1, wb1, oacc[n], 0, 0, 0);
            }
        }
        // ---- epilogue: out = (H @ W2^T + b2) * e^s
#pragma unroll
        for (int n = 0; n < 4; ++n) {
#pragma unroll
            for (int reg = 0; reg < 4; ++reg) {
                float o = (oacc[n][reg] + bias2[n]) * sc[reg];
                out[(m0 + wave * 16 + q * 4 + reg) * 64 + n * 16 + l16] = o;
            }
        }
    }
}

extern "C" void kernel_launch(void* const* d_in, const int* in_sizes, int n_in,
                              void* d_out, int out_size, void* d_ws, size_t ws_size,
                              hipStream_t stream) {
    const float* x  = (const float*)d_in[0];
    const float* r  = (const float*)d_in[1];
    const float* W1 = (const float*)d_in[2];
    const float* b1 = (const float*)d_in[3];
    const float* W2 = (const float*)d_in[4];
    const float* b2 = (const float*)d_in[5];
    float* out = (float*)d_out;
    int B = in_sizes[0] / 64;  // 262144

    char* ws = (char*)d_ws;
    unsigned short* w1b = (unsigned short*)ws;            // 32768 B
    unsigned short* w2b = (unsigned short*)(ws + 32768);  // 32768 B

    convert_w_k<<<64, 256, 0, stream>>>(W1, W2, w1b, w2b);

    int tiles = B / 64;        // 4096
    int blocks = 1024;         // grid-stride: 4 tiles each
    int tpb = tiles / blocks;  // 4
    fused_k<<<blocks, 256, 0, stream>>>(x, r, w1b, w2b, b1, b2, out, tpb);
}